// Round 1
// baseline (362.531 us; speedup 1.0000x reference)
//
#include <hip/hip_runtime.h>
#include <stdint.h>

// Problem constants (match reference setup_inputs)
#define TOTAL  262144      // B*N = 16*16384
#define HALF   131072      // TOTAL/2 for threefry counter split
#define G      1024        // NUM_GROUPS
#define NBINS  1025        // groups 0..1023 + sentinel 1024 (masked)
#define NCHUNK 512         // chunks for counting sort
#define CHUNK  512         // elements per chunk
#define D2     64          // float2 per embedding row (D=128)

// workspace layout (bytes)
#define OFF_COUNTS 0               // int[1025]
#define OFF_STARTS 8192            // int[1025]
#define OFF_FLAG   16384           // int: 1 => mask stored as bytes, 0 => int32
#define OFF_VT     16388           // int: valid_total
#define OFF_LOSS   16392           // double
#define OFF_VALID  16400           // double
#define OFF_ORDER  16448           // int[TOTAL]
#define OFF_GHIST  1065024         // int[NBINS*NCHUNK]  (~2.1 MB), g-major

// ---------------- threefry2x32 (JAX-compatible) ----------------
__device__ __forceinline__ void threefry2x32(uint32_t k0, uint32_t k1,
                                             uint32_t& x0, uint32_t& x1) {
  uint32_t ks0 = k0, ks1 = k1, ks2 = k0 ^ k1 ^ 0x1BD11BDAu;
#define TF_RND(R) { x0 += x1; x1 = (x1 << (R)) | (x1 >> (32 - (R))); x1 ^= x0; }
  x0 += ks0; x1 += ks1;
  TF_RND(13) TF_RND(15) TF_RND(26) TF_RND(6)
  x0 += ks1; x1 += ks2 + 1u;
  TF_RND(17) TF_RND(29) TF_RND(16) TF_RND(24)
  x0 += ks2; x1 += ks0 + 2u;
  TF_RND(13) TF_RND(15) TF_RND(26) TF_RND(6)
  x0 += ks0; x1 += ks1 + 3u;
  TF_RND(17) TF_RND(29) TF_RND(16) TF_RND(24)
  x0 += ks1; x1 += ks2 + 4u;
  TF_RND(13) TF_RND(15) TF_RND(26) TF_RND(6)
  x0 += ks2; x1 += ks0 + 5u;
#undef TF_RND
}

__device__ __forceinline__ int load_mask(const void* mask, int is8, int j) {
  return is8 ? (int)((const unsigned char*)mask)[j] : ((const int*)mask)[j];
}

// K0: detect mask storage. int32 storage of 0/1 => all bytes at (i%4)!=0 are 0.
__global__ void k_probe_mask(const unsigned char* mb, int* flag) {
  int t = threadIdx.x;
  if ((t & 3) != 0 && mb[t] != 0) atomicOr(flag, 1);
}

// K1: per-chunk histogram -> ghist[g*NCHUNK + chunk]; also global counts.
__global__ __launch_bounds__(CHUNK) void k_hist(const int* __restrict__ groups,
                                                const void* __restrict__ mask,
                                                const int* __restrict__ flag,
                                                int* __restrict__ counts,
                                                int* __restrict__ ghist) {
  __shared__ int h[NBINS];
  int t = threadIdx.x;
  for (int b = t; b < NBINS; b += CHUNK) h[b] = 0;
  __syncthreads();
  int is8 = *flag;
  int j = blockIdx.x * CHUNK + t;
  int m = load_mask(mask, is8, j);
  int g = m ? groups[j] : G;
  atomicAdd(&h[g], 1);
  __syncthreads();
  for (int b = t; b < NBINS; b += CHUNK) {
    int v = h[b];
    ghist[b * NCHUNK + blockIdx.x] = v;
    if (v) atomicAdd(&counts[b], v);
  }
}

// K2: exclusive scan of counts -> starts; valid_total.
__global__ __launch_bounds__(1024) void k_scan(const int* __restrict__ counts,
                                               int* __restrict__ starts,
                                               int* __restrict__ vt) {
  __shared__ int buf[1024];
  int t = threadIdx.x;
  buf[t] = counts[t];
  __syncthreads();
  for (int off = 1; off < 1024; off <<= 1) {
    int v = buf[t];
    if (t >= off) v += buf[t - off];
    __syncthreads();
    buf[t] = v;
    __syncthreads();
  }
  starts[t] = (t == 0) ? 0 : buf[t - 1];
  if (t == 0) {
    starts[1024] = buf[1023];
    *vt = TOTAL - counts[1024];
  }
}

// K3: per-group exclusive scan over chunks (wave per group): ghist becomes chunk base.
__global__ __launch_bounds__(256) void k_rebase(const int* __restrict__ starts,
                                                int* __restrict__ ghist) {
  int wave = threadIdx.x >> 6, lane = threadIdx.x & 63;
  int g = blockIdx.x * 4 + wave;
  if (g >= NBINS) return;
  int* row = ghist + g * NCHUNK;
  int v[8];
  int s = 0;
  int bi = lane * 8;
#pragma unroll
  for (int k = 0; k < 8; k++) { v[k] = row[bi + k]; s += v[k]; }
  int incl = s;
  for (int d = 1; d < 64; d <<= 1) {
    int tt = __shfl_up(incl, d);
    if (lane >= d) incl += tt;
  }
  int run = starts[g] + (incl - s);
#pragma unroll
  for (int k = 0; k < 8; k++) { int tt = v[k]; row[bi + k] = run; run += tt; }
}

// K4: stable rank within chunk + scatter -> order[sorted_pos] = original index.
__global__ __launch_bounds__(CHUNK) void k_scatter(const int* __restrict__ groups,
                                                   const void* __restrict__ mask,
                                                   const int* __restrict__ flag,
                                                   const int* __restrict__ ghist,
                                                   int* __restrict__ order) {
  __shared__ int gl[CHUNK];
  int t = threadIdx.x;
  int is8 = *flag;
  int j = blockIdx.x * CHUNK + t;
  int m = load_mask(mask, is8, j);
  int g = m ? groups[j] : G;
  gl[t] = g;
  __syncthreads();
  int rank = 0;
  for (int t2 = 0; t2 < CHUNK; t2++) {      // broadcast LDS reads
    int gg = gl[t2];
    rank += (t2 < t && gg == g) ? 1 : 0;
  }
  int pos = ghist[g * NCHUNK + blockIdx.x] + rank;
  order[pos] = j;
}

// K5: main. Phase A: per-thread anchor metadata (threefry neg sampling).
//     Phase B: wave-per-anchor dot products + softplus + accumulate.
__global__ __launch_bounds__(256) void k_main(const float* __restrict__ emb,
                                              const int* __restrict__ groups,
                                              const void* __restrict__ mask,
                                              const int* __restrict__ flag,
                                              const int* __restrict__ counts,
                                              const int* __restrict__ starts,
                                              const int* __restrict__ vtp,
                                              const int* __restrict__ order,
                                              double* __restrict__ lossAcc,
                                              double* __restrict__ validAcc) {
  __shared__ int mA[256], mP[256], mN[256], mV[256];
  int t = threadIdx.x;
  int i = blockIdx.x * 256 + t;
  int is8 = *flag;
  int j = order[i];
  int mm = load_mask(mask, is8, j);
  int g = mm ? groups[j] : G;
  int cnt = counts[g], st = starts[g];
  int local = i - st;
  int partner = (local == 0) ? (cnt - 1) : (local - 1);
  int pos_idx = order[st + partner];

  uint32_t x0, x1;
  if (i < HALF) { x0 = (uint32_t)i; x1 = (uint32_t)(i + HALF); }
  else          { x0 = (uint32_t)(i - HALF); x1 = (uint32_t)i; }
  threefry2x32(0u, 42u, x0, x1);
  uint32_t bits = (i < HALF) ? x0 : x1;
  float u = __uint_as_float((bits >> 9) | 0x3F800000u) - 1.0f;

  int vt = *vtp;
  int compi = vt - cnt;
  int comp = compi > 1 ? compi : 1;
  int r = (int)(u * (float)comp);
  int cm1 = comp - 1;
  if (r > cm1) r = cm1;
  int neg_pos = (r < st) ? r : (r + cnt);
  if (neg_pos < 0) neg_pos = 0;
  if (neg_pos > TOTAL - 1) neg_pos = TOTAL - 1;
  int neg_idx = order[neg_pos];
  int valid = (g < G) && (cnt >= 2) && (compi > 0);

  mA[t] = j; mP[t] = pos_idx; mN[t] = neg_idx; mV[t] = valid;
  __syncthreads();

  int wave = t >> 6, lane = t & 63;
  const float2* e2 = (const float2*)emb;
  float lsum = 0.f, vsum = 0.f;
  for (int k = 0; k < 64; k++) {
    int mi = wave * 64 + k;
    int ai = mA[mi], pi = mP[mi], ni = mN[mi], vv = mV[mi];
    float2 av = e2[(size_t)ai * D2 + lane];
    float2 pv = e2[(size_t)pi * D2 + lane];
    float2 nv = e2[(size_t)ni * D2 + lane];
    float ap = av.x * pv.x + av.y * pv.y;
    float an = av.x * nv.x + av.y * nv.y;
    for (int d = 32; d >= 1; d >>= 1) {
      ap += __shfl_xor(ap, d);
      an += __shfl_xor(an, d);
    }
    if (vv) {
      float ps = ap * 10.0f, ns = an * 10.0f;   // 1/TEMPERATURE
      float dd = ns - ps;
      float li = fmaxf(dd, 0.0f) + log1pf(expf(-fabsf(dd)));
      lsum += li; vsum += 1.0f;
    }
  }
  if (lane == 0) {
    atomicAdd(lossAcc, (double)lsum);
    atomicAdd(validAcc, (double)vsum);
  }
}

// K6: finalize loss = sum / max(valid, 1)
__global__ void k_final(const double* lossAcc, const double* validAcc, float* out) {
  double v = *validAcc;
  if (v < 1.0) v = 1.0;
  out[0] = (float)(*lossAcc / v);
}

extern "C" void kernel_launch(void* const* d_in, const int* in_sizes, int n_in,
                              void* d_out, int out_size, void* d_ws, size_t ws_size,
                              hipStream_t stream) {
  const float* emb = (const float*)d_in[0];
  const int* groups = (const int*)d_in[1];
  const void* mask = d_in[2];
  float* out = (float*)d_out;

  char* ws = (char*)d_ws;
  int* counts = (int*)(ws + OFF_COUNTS);
  int* starts = (int*)(ws + OFF_STARTS);
  int* flag = (int*)(ws + OFF_FLAG);
  int* vt = (int*)(ws + OFF_VT);
  double* lossAcc = (double*)(ws + OFF_LOSS);
  double* validAcc = (double*)(ws + OFF_VALID);
  int* order = (int*)(ws + OFF_ORDER);
  int* ghist = (int*)(ws + OFF_GHIST);

  // zero counts + flag + accumulators (ws is poisoned 0xAA before each launch)
  hipMemsetAsync(ws, 0, 16408, stream);

  k_probe_mask<<<1, 1024, 0, stream>>>((const unsigned char*)mask, flag);
  k_hist<<<NCHUNK, CHUNK, 0, stream>>>(groups, mask, flag, counts, ghist);
  k_scan<<<1, 1024, 0, stream>>>(counts, starts, vt);
  k_rebase<<<(NBINS + 3) / 4, 256, 0, stream>>>(starts, ghist);
  k_scatter<<<NCHUNK, CHUNK, 0, stream>>>(groups, mask, flag, ghist, order);
  k_main<<<TOTAL / 256, 256, 0, stream>>>(emb, groups, mask, flag, counts, starts,
                                          vt, order, lossAcc, validAcc);
  k_final<<<1, 1, 0, stream>>>(lossAcc, validAcc, out);
}

// Round 2
// 322.010 us; speedup vs baseline: 1.1258x; 1.1258x over previous
//
#include <hip/hip_runtime.h>
#include <stdint.h>

// Problem constants (match reference setup_inputs)
#define TOTAL  262144      // B*N = 16*16384
#define HALF   131072      // TOTAL/2 for threefry counter split
#define G      1024        // NUM_GROUPS
#define NBINS  1025        // groups 0..1023 + sentinel 1024 (masked)
#define NCHUNK 512         // chunks for counting sort
#define CHUNK  512         // elements per chunk

// workspace layout (bytes)
#define OFF_COUNTS 0               // int[1025]
#define OFF_STARTS 8192            // int[1025]
#define OFF_FLAG   16384           // int: 1 => mask stored as bytes, 0 => int32
#define OFF_VT     16388           // int: valid_total
#define OFF_LOSS   16392           // double
#define OFF_VALID  16400           // double
#define OFF_ORDER  16448           // int[TOTAL]
#define OFF_GHIST  1065024         // int[NBINS*NCHUNK]  (~2.1 MB), g-major

// ---------------- threefry2x32 (JAX-compatible) ----------------
__device__ __forceinline__ void threefry2x32(uint32_t k0, uint32_t k1,
                                             uint32_t& x0, uint32_t& x1) {
  uint32_t ks0 = k0, ks1 = k1, ks2 = k0 ^ k1 ^ 0x1BD11BDAu;
#define TF_RND(R) { x0 += x1; x1 = (x1 << (R)) | (x1 >> (32 - (R))); x1 ^= x0; }
  x0 += ks0; x1 += ks1;
  TF_RND(13) TF_RND(15) TF_RND(26) TF_RND(6)
  x0 += ks1; x1 += ks2 + 1u;
  TF_RND(17) TF_RND(29) TF_RND(16) TF_RND(24)
  x0 += ks2; x1 += ks0 + 2u;
  TF_RND(13) TF_RND(15) TF_RND(26) TF_RND(6)
  x0 += ks0; x1 += ks1 + 3u;
  TF_RND(17) TF_RND(29) TF_RND(16) TF_RND(24)
  x0 += ks1; x1 += ks2 + 4u;
  TF_RND(13) TF_RND(15) TF_RND(26) TF_RND(6)
  x0 += ks2; x1 += ks0 + 5u;
#undef TF_RND
}

__device__ __forceinline__ int load_mask(const void* mask, int is8, int j) {
  return is8 ? (int)((const unsigned char*)mask)[j] : ((const int*)mask)[j];
}

// K0: detect mask storage. int32 storage of 0/1 => all bytes at (i%4)!=0 are 0.
__global__ void k_probe_mask(const unsigned char* mb, int* flag) {
  int t = threadIdx.x;
  if ((t & 3) != 0 && mb[t] != 0) atomicOr(flag, 1);
}

// K1: per-chunk histogram -> ghist[g*NCHUNK + chunk]; also global counts.
__global__ __launch_bounds__(CHUNK) void k_hist(const int* __restrict__ groups,
                                                const void* __restrict__ mask,
                                                const int* __restrict__ flag,
                                                int* __restrict__ counts,
                                                int* __restrict__ ghist) {
  __shared__ int h[NBINS];
  int t = threadIdx.x;
  for (int b = t; b < NBINS; b += CHUNK) h[b] = 0;
  __syncthreads();
  int is8 = *flag;
  int j = blockIdx.x * CHUNK + t;
  int m = load_mask(mask, is8, j);
  int g = m ? groups[j] : G;
  atomicAdd(&h[g], 1);
  __syncthreads();
  for (int b = t; b < NBINS; b += CHUNK) {
    int v = h[b];
    ghist[b * NCHUNK + blockIdx.x] = v;
    if (v) atomicAdd(&counts[b], v);
  }
}

// K2: exclusive scan of counts -> starts; valid_total. Single wave, no barriers.
__global__ __launch_bounds__(64) void k_scan(const int* __restrict__ counts,
                                             int* __restrict__ starts,
                                             int* __restrict__ vt) {
  int l = threadIdx.x;     // 64 lanes, 16 bins each (bins 0..1023)
  int c[16];
  int s = 0;
#pragma unroll
  for (int k = 0; k < 16; k++) { c[k] = counts[l * 16 + k]; s += c[k]; }
  int incl = s;
  for (int d = 1; d < 64; d <<= 1) {
    int tt = __shfl_up(incl, d);
    if (l >= d) incl += tt;
  }
  int run = incl - s;      // exclusive prefix
#pragma unroll
  for (int k = 0; k < 16; k++) { starts[l * 16 + k] = run; run += c[k]; }
  if (l == 63) starts[1024] = run;           // sum of bins 0..1023
  if (l == 0) *vt = TOTAL - counts[1024];
}

// K3: per-group exclusive scan over chunks (wave per group): ghist becomes chunk base.
__global__ __launch_bounds__(256) void k_rebase(const int* __restrict__ starts,
                                                int* __restrict__ ghist) {
  int wave = threadIdx.x >> 6, lane = threadIdx.x & 63;
  int g = blockIdx.x * 4 + wave;
  if (g >= NBINS) return;
  int* row = ghist + g * NCHUNK;
  int v[8];
  int s = 0;
  int bi = lane * 8;
#pragma unroll
  for (int k = 0; k < 8; k++) { v[k] = row[bi + k]; s += v[k]; }
  int incl = s;
  for (int d = 1; d < 64; d <<= 1) {
    int tt = __shfl_up(incl, d);
    if (lane >= d) incl += tt;
  }
  int run = starts[g] + (incl - s);
#pragma unroll
  for (int k = 0; k < 8; k++) { int tt = v[k]; row[bi + k] = run; run += tt; }
}

// K4: stable rank within chunk + scatter -> order[sorted_pos] = original index.
__global__ __launch_bounds__(CHUNK) void k_scatter(const int* __restrict__ groups,
                                                   const void* __restrict__ mask,
                                                   const int* __restrict__ flag,
                                                   const int* __restrict__ ghist,
                                                   int* __restrict__ order) {
  __shared__ int gl[CHUNK];
  int t = threadIdx.x;
  int is8 = *flag;
  int j = blockIdx.x * CHUNK + t;
  int m = load_mask(mask, is8, j);
  int g = m ? groups[j] : G;
  gl[t] = g;
  __syncthreads();
  int rank = 0;
  for (int t2 = 0; t2 < t; t2++)            // broadcast LDS reads, trip = t
    rank += (gl[t2] == g) ? 1 : 0;
  int pos = ghist[g * NCHUNK + blockIdx.x] + rank;
  order[pos] = j;
}

// K5: main. Phase A: per-thread anchor metadata (threefry neg sampling).
//     Phase B: 8 lanes per anchor -> 8 anchors in flight per wave iteration.
__global__ __launch_bounds__(256) void k_main(const float* __restrict__ emb,
                                              const int* __restrict__ groups,
                                              const void* __restrict__ mask,
                                              const int* __restrict__ flag,
                                              const int* __restrict__ counts,
                                              const int* __restrict__ starts,
                                              const int* __restrict__ vtp,
                                              const int* __restrict__ order,
                                              double* __restrict__ lossAcc,
                                              double* __restrict__ validAcc) {
  __shared__ int mA[256], mP[256], mN[256], mV[256];
  int t = threadIdx.x;
  int i = blockIdx.x * 256 + t;
  int is8 = *flag;
  int j = order[i];
  int mm = load_mask(mask, is8, j);
  int g = mm ? groups[j] : G;
  int cnt = counts[g], st = starts[g];
  int local = i - st;
  int partner = (local == 0) ? (cnt - 1) : (local - 1);
  int pos_idx = order[st + partner];

  uint32_t x0, x1;
  if (i < HALF) { x0 = (uint32_t)i; x1 = (uint32_t)(i + HALF); }
  else          { x0 = (uint32_t)(i - HALF); x1 = (uint32_t)i; }
  threefry2x32(0u, 42u, x0, x1);
  uint32_t bits = (i < HALF) ? x0 : x1;
  float u = __uint_as_float((bits >> 9) | 0x3F800000u) - 1.0f;

  int vt = *vtp;
  int compi = vt - cnt;
  int comp = compi > 1 ? compi : 1;
  int r = (int)(u * (float)comp);
  int cm1 = comp - 1;
  if (r > cm1) r = cm1;
  int neg_pos = (r < st) ? r : (r + cnt);
  if (neg_pos < 0) neg_pos = 0;
  if (neg_pos > TOTAL - 1) neg_pos = TOTAL - 1;
  int neg_idx = order[neg_pos];
  int valid = (g < G) && (cnt >= 2) && (compi > 0);

  mA[t] = j; mP[t] = pos_idx; mN[t] = neg_idx; mV[t] = valid;
  __syncthreads();

  int wave = t >> 6, lane = t & 63;
  int sg = lane >> 3;       // anchor slot 0..7 within iteration
  int sl = lane & 7;        // sub-lane 0..7, covers floats [sl*16, sl*16+16)
  const float4* e4 = (const float4*)emb;   // row stride = 32 float4
  float lsum = 0.f, vsum = 0.f;
#pragma unroll 2
  for (int it = 0; it < 8; it++) {
    int mi = wave * 64 + it * 8 + sg;
    int ai = mA[mi], pi = mP[mi], ni = mN[mi], vv = mV[mi];
    const float4* ar = e4 + (size_t)ai * 32 + sl * 4;
    const float4* pr = e4 + (size_t)pi * 32 + sl * 4;
    const float4* nr = e4 + (size_t)ni * 32 + sl * 4;
    float ap = 0.f, an = 0.f;
#pragma unroll
    for (int k = 0; k < 4; k++) {
      float4 av = ar[k];
      float4 pv = pr[k];
      float4 nv = nr[k];
      ap += av.x * pv.x + av.y * pv.y + av.z * pv.z + av.w * pv.w;
      an += av.x * nv.x + av.y * nv.y + av.z * nv.z + av.w * nv.w;
    }
    ap += __shfl_xor(ap, 4); an += __shfl_xor(an, 4);
    ap += __shfl_xor(ap, 2); an += __shfl_xor(an, 2);
    ap += __shfl_xor(ap, 1); an += __shfl_xor(an, 1);
    if (vv && sl == 0) {
      float ps = ap * 10.0f, ns = an * 10.0f;   // 1/TEMPERATURE
      float dd = ns - ps;
      float li = fmaxf(dd, 0.0f) + log1pf(expf(-fabsf(dd)));
      lsum += li; vsum += 1.0f;
    }
  }
  for (int d = 32; d >= 1; d >>= 1) {
    lsum += __shfl_xor(lsum, d);
    vsum += __shfl_xor(vsum, d);
  }
  if (lane == 0) {
    atomicAdd(lossAcc, (double)lsum);
    atomicAdd(validAcc, (double)vsum);
  }
}

// K6: finalize loss = sum / max(valid, 1)
__global__ void k_final(const double* lossAcc, const double* validAcc, float* out) {
  double v = *validAcc;
  if (v < 1.0) v = 1.0;
  out[0] = (float)(*lossAcc / v);
}

extern "C" void kernel_launch(void* const* d_in, const int* in_sizes, int n_in,
                              void* d_out, int out_size, void* d_ws, size_t ws_size,
                              hipStream_t stream) {
  const float* emb = (const float*)d_in[0];
  const int* groups = (const int*)d_in[1];
  const void* mask = d_in[2];
  float* out = (float*)d_out;

  char* ws = (char*)d_ws;
  int* counts = (int*)(ws + OFF_COUNTS);
  int* starts = (int*)(ws + OFF_STARTS);
  int* flag = (int*)(ws + OFF_FLAG);
  int* vt = (int*)(ws + OFF_VT);
  double* lossAcc = (double*)(ws + OFF_LOSS);
  double* validAcc = (double*)(ws + OFF_VALID);
  int* order = (int*)(ws + OFF_ORDER);
  int* ghist = (int*)(ws + OFF_GHIST);

  // zero counts + flag + accumulators (ws is poisoned 0xAA before each launch)
  hipMemsetAsync(ws, 0, 16408, stream);

  k_probe_mask<<<1, 1024, 0, stream>>>((const unsigned char*)mask, flag);
  k_hist<<<NCHUNK, CHUNK, 0, stream>>>(groups, mask, flag, counts, ghist);
  k_scan<<<1, 64, 0, stream>>>(counts, starts, vt);
  k_rebase<<<(NBINS + 3) / 4, 256, 0, stream>>>(starts, ghist);
  k_scatter<<<NCHUNK, CHUNK, 0, stream>>>(groups, mask, flag, ghist, order);
  k_main<<<TOTAL / 256, 256, 0, stream>>>(emb, groups, mask, flag, counts, starts,
                                          vt, order, lossAcc, validAcc);
  k_final<<<1, 1, 0, stream>>>(lossAcc, validAcc, out);
}

// Round 3
// 318.115 us; speedup vs baseline: 1.1396x; 1.0122x over previous
//
#include <hip/hip_runtime.h>
#include <stdint.h>

// Problem constants (match reference setup_inputs)
#define TOTAL  262144      // B*N = 16*16384
#define HALF   131072      // TOTAL/2 for threefry counter split
#define G      1024        // NUM_GROUPS
#define NBINS  1025        // groups 0..1023 + sentinel 1024 (masked)
#define NCHUNK 512         // chunks for counting sort
#define CHUNK  512         // elements per chunk

// workspace layout (bytes)
#define OFF_COUNTS 0               // int[1025]
#define OFF_STARTS 8192            // int[1025]
#define OFF_VT     16388           // int: valid_total
#define OFF_LOSS   16392           // double
#define OFF_VALID  16400           // double
#define OFF_ORDER  16448           // int[TOTAL]
#define OFF_GHIST  1065024         // int[NBINS*NCHUNK]  (~2.1 MB), g-major

// ---------------- threefry2x32 (JAX-compatible) ----------------
__device__ __forceinline__ void threefry2x32(uint32_t k0, uint32_t k1,
                                             uint32_t& x0, uint32_t& x1) {
  uint32_t ks0 = k0, ks1 = k1, ks2 = k0 ^ k1 ^ 0x1BD11BDAu;
#define TF_RND(R) { x0 += x1; x1 = (x1 << (R)) | (x1 >> (32 - (R))); x1 ^= x0; }
  x0 += ks0; x1 += ks1;
  TF_RND(13) TF_RND(15) TF_RND(26) TF_RND(6)
  x0 += ks1; x1 += ks2 + 1u;
  TF_RND(17) TF_RND(29) TF_RND(16) TF_RND(24)
  x0 += ks2; x1 += ks0 + 2u;
  TF_RND(13) TF_RND(15) TF_RND(26) TF_RND(6)
  x0 += ks0; x1 += ks1 + 3u;
  TF_RND(17) TF_RND(29) TF_RND(16) TF_RND(24)
  x0 += ks1; x1 += ks2 + 4u;
  TF_RND(13) TF_RND(15) TF_RND(26) TF_RND(6)
  x0 += ks2; x1 += ks0 + 5u;
#undef TF_RND
}

__device__ __forceinline__ int load_mask(const void* mask, int is8, int j) {
  return is8 ? (int)((const unsigned char*)mask)[j] : ((const int*)mask)[j];
}

// Per-wave self-detection of mask storage: int32 storage of 0/1 => all bytes
// at (addr%4)!=0 are zero. Probe bytes [0,256): 64 lanes x uchar4. In byte
// mode ~192 random 0/1 bytes => P(all zero) ~ 2^-192.
__device__ __forceinline__ int detect_is8(const void* mask) {
  int lane = threadIdx.x & 63;
  uchar4 p = ((const uchar4*)mask)[lane];
  unsigned long long bal = __ballot((p.y | p.z | p.w) != 0);
  return bal != 0ull;
}

// K1: per-chunk histogram -> ghist[g*NCHUNK + chunk]; also global counts.
__global__ __launch_bounds__(CHUNK) void k_hist(const int* __restrict__ groups,
                                                const void* __restrict__ mask,
                                                int* __restrict__ counts,
                                                int* __restrict__ ghist) {
  __shared__ int h[NBINS];
  int t = threadIdx.x;
  int is8 = detect_is8(mask);
  for (int b = t; b < NBINS; b += CHUNK) h[b] = 0;
  __syncthreads();
  int j = blockIdx.x * CHUNK + t;
  int m = load_mask(mask, is8, j);
  int g = m ? groups[j] : G;
  atomicAdd(&h[g], 1);
  __syncthreads();
  for (int b = t; b < NBINS; b += CHUNK) {
    int v = h[b];
    ghist[b * NCHUNK + blockIdx.x] = v;
    if (v) atomicAdd(&counts[b], v);
  }
}

// K2: exclusive scan of counts -> starts; valid_total. Single wave, no barriers.
__global__ __launch_bounds__(64) void k_scan(const int* __restrict__ counts,
                                             int* __restrict__ starts,
                                             int* __restrict__ vt) {
  int l = threadIdx.x;     // 64 lanes, 16 bins each (bins 0..1023)
  int c[16];
  int s = 0;
#pragma unroll
  for (int k = 0; k < 16; k++) { c[k] = counts[l * 16 + k]; s += c[k]; }
  int incl = s;
  for (int d = 1; d < 64; d <<= 1) {
    int tt = __shfl_up(incl, d);
    if (l >= d) incl += tt;
  }
  int run = incl - s;      // exclusive prefix
#pragma unroll
  for (int k = 0; k < 16; k++) { starts[l * 16 + k] = run; run += c[k]; }
  if (l == 63) starts[1024] = run;           // sum of bins 0..1023
  if (l == 0) *vt = TOTAL - counts[1024];
}

// K3: per-group exclusive scan over chunks (wave per group): ghist becomes chunk base.
__global__ __launch_bounds__(256) void k_rebase(const int* __restrict__ starts,
                                                int* __restrict__ ghist) {
  int wave = threadIdx.x >> 6, lane = threadIdx.x & 63;
  int g = blockIdx.x * 4 + wave;
  if (g >= NBINS) return;
  int* row = ghist + g * NCHUNK;
  int v[8];
  int s = 0;
  int bi = lane * 8;
#pragma unroll
  for (int k = 0; k < 8; k++) { v[k] = row[bi + k]; s += v[k]; }
  int incl = s;
  for (int d = 1; d < 64; d <<= 1) {
    int tt = __shfl_up(incl, d);
    if (lane >= d) incl += tt;
  }
  int run = starts[g] + (incl - s);
#pragma unroll
  for (int k = 0; k < 8; k++) { int tt = v[k]; row[bi + k] = run; run += tt; }
}

// K4: stable rank + scatter. Rank via 11-bit ballot match-any (O(11) per
// thread) + per-wave leader counts in LDS, instead of O(t) serial loop.
__global__ __launch_bounds__(CHUNK) void k_scatter(const int* __restrict__ groups,
                                                   const void* __restrict__ mask,
                                                   const int* __restrict__ ghist,
                                                   int* __restrict__ order) {
  __shared__ int h[8][NBINS];          // 32.8 KB
  int t = threadIdx.x;
  int wave = t >> 6, lane = t & 63;
  int is8 = detect_is8(mask);
  int j = blockIdx.x * CHUNK + t;
  int m = load_mask(mask, is8, j);
  int g = m ? groups[j] : G;
  for (int idx = t; idx < 8 * NBINS; idx += CHUNK) ((int*)h)[idx] = 0;
  __syncthreads();
  // match-any over 11 bits of g (0..1024)
  unsigned long long mm = ~0ull;
#pragma unroll
  for (int b = 0; b < 11; b++) {
    unsigned long long bal = __ballot(((g >> b) & 1) != 0);
    mm &= ((g >> b) & 1) ? bal : ~bal;
  }
  unsigned long long lt = (1ull << lane) - 1ull;
  int lanerank = __popcll(mm & lt);
  if (lanerank == 0) h[wave][g] = __popcll(mm);   // unique (wave,g) writer
  __syncthreads();
  int rank = lanerank;
  for (int w = 0; w < wave; w++) rank += h[w][g];
  int pos = ghist[g * NCHUNK + blockIdx.x] + rank;
  order[pos] = j;
}

// K5: main. Wave handles 32 sorted positions (4 iters x 8 anchors, 8 lanes each).
// Positive row of position i == anchor row of i-1 => fetched from the neighbor
// lane-group's registers via __shfl_up(.,8); gather fallback for sg==0 / wraps.
__global__ __launch_bounds__(256) void k_main(const float* __restrict__ emb,
                                              const int* __restrict__ groups,
                                              const void* __restrict__ mask,
                                              const int* __restrict__ counts,
                                              const int* __restrict__ starts,
                                              const int* __restrict__ vtp,
                                              const int* __restrict__ order,
                                              double* __restrict__ lossAcc,
                                              double* __restrict__ validAcc) {
  __shared__ int mA[128], mP[128], mN[128], mF[128];
  __shared__ float bl[4], bv[4];
  int t = threadIdx.x;
  int wave = t >> 6, lane = t & 63;
  int is8 = detect_is8(mask);
  int P0 = blockIdx.x * 128;

  // ---- Phase A: lanes 0..31 compute metadata for position P0 + wave*32 + lane
  if (lane < 32) {
    int i = P0 + wave * 32 + lane;
    int j = order[i];
    int mm2 = load_mask(mask, is8, j);
    int g = mm2 ? groups[j] : G;
    int cnt = counts[g], st = starts[g];
    int local = i - st;
    int partner_pos = (local == 0) ? (st + cnt - 1) : (i - 1);
    int pos_idx = order[partner_pos];

    uint32_t x0, x1;
    if (i < HALF) { x0 = (uint32_t)i; x1 = (uint32_t)(i + HALF); }
    else          { x0 = (uint32_t)(i - HALF); x1 = (uint32_t)i; }
    threefry2x32(0u, 42u, x0, x1);
    uint32_t bits = (i < HALF) ? x0 : x1;
    float u = __uint_as_float((bits >> 9) | 0x3F800000u) - 1.0f;

    int vt = *vtp;
    int compi = vt - cnt;
    int comp = compi > 1 ? compi : 1;
    int r = (int)(u * (float)comp);
    int cm1 = comp - 1;
    if (r > cm1) r = cm1;
    int neg_pos = (r < st) ? r : (r + cnt);
    if (neg_pos < 0) neg_pos = 0;
    if (neg_pos > TOTAL - 1) neg_pos = TOTAL - 1;
    int neg_idx = order[neg_pos];
    int valid = (g < G) && (cnt >= 2) && (compi > 0);
    int shufok = (partner_pos == i - 1);

    int slot = wave * 32 + lane;
    mA[slot] = j; mP[slot] = pos_idx; mN[slot] = neg_idx;
    mF[slot] = valid | (shufok << 1);
  }
  __syncthreads();

  // ---- Phase B
  int sg = lane >> 3, sl = lane & 7;
  const float4* e4 = (const float4*)emb;   // row stride = 32 float4
  float lsum = 0.f, vsum = 0.f;
#pragma unroll 1
  for (int it = 0; it < 4; it++) {
    int slot = wave * 32 + it * 8 + sg;
    int ai = mA[slot], pi = mP[slot], ni = mN[slot], fl = mF[slot];
    const float4* ar = e4 + (size_t)ai * 32 + sl * 4;
    const float4* nr = e4 + (size_t)ni * 32 + sl * 4;
    float4 a0 = ar[0], a1 = ar[1], a2 = ar[2], a3 = ar[3];
    float4 n0 = nr[0], n1 = nr[1], n2 = nr[2], n3 = nr[3];
    // positive fragment = neighbor group's anchor fragment
    float4 p0, p1, p2, p3;
    p0.x = __shfl_up(a0.x, 8); p0.y = __shfl_up(a0.y, 8);
    p0.z = __shfl_up(a0.z, 8); p0.w = __shfl_up(a0.w, 8);
    p1.x = __shfl_up(a1.x, 8); p1.y = __shfl_up(a1.y, 8);
    p1.z = __shfl_up(a1.z, 8); p1.w = __shfl_up(a1.w, 8);
    p2.x = __shfl_up(a2.x, 8); p2.y = __shfl_up(a2.y, 8);
    p2.z = __shfl_up(a2.z, 8); p2.w = __shfl_up(a2.w, 8);
    p3.x = __shfl_up(a3.x, 8); p3.y = __shfl_up(a3.y, 8);
    p3.z = __shfl_up(a3.z, 8); p3.w = __shfl_up(a3.w, 8);
    int useshuf = (sg > 0) && (fl & 2);
    if (!useshuf) {
      const float4* pr = e4 + (size_t)pi * 32 + sl * 4;
      p0 = pr[0]; p1 = pr[1]; p2 = pr[2]; p3 = pr[3];
    }
    float ap0 = a0.x*p0.x + a0.y*p0.y + a0.z*p0.z + a0.w*p0.w
              + a1.x*p1.x + a1.y*p1.y + a1.z*p1.z + a1.w*p1.w;
    float ap1 = a2.x*p2.x + a2.y*p2.y + a2.z*p2.z + a2.w*p2.w
              + a3.x*p3.x + a3.y*p3.y + a3.z*p3.z + a3.w*p3.w;
    float an0 = a0.x*n0.x + a0.y*n0.y + a0.z*n0.z + a0.w*n0.w
              + a1.x*n1.x + a1.y*n1.y + a1.z*n1.z + a1.w*n1.w;
    float an1 = a2.x*n2.x + a2.y*n2.y + a2.z*n2.z + a2.w*n2.w
              + a3.x*n3.x + a3.y*n3.y + a3.z*n3.z + a3.w*n3.w;
    float ap = ap0 + ap1, an = an0 + an1;
    ap += __shfl_xor(ap, 4); an += __shfl_xor(an, 4);
    ap += __shfl_xor(ap, 2); an += __shfl_xor(an, 2);
    ap += __shfl_xor(ap, 1); an += __shfl_xor(an, 1);
    if ((fl & 1) && sl == 0) {
      float ps = ap * 10.0f, ns = an * 10.0f;   // 1/TEMPERATURE
      float dd = ns - ps;
      float li = fmaxf(dd, 0.0f) + log1pf(expf(-fabsf(dd)));
      lsum += li; vsum += 1.0f;
    }
  }
  // wave reduce, then one atomic pair per block
  for (int d = 32; d >= 1; d >>= 1) {
    lsum += __shfl_xor(lsum, d);
    vsum += __shfl_xor(vsum, d);
  }
  if (lane == 0) { bl[wave] = lsum; bv[wave] = vsum; }
  __syncthreads();
  if (t == 0) {
    float L = bl[0] + bl[1] + bl[2] + bl[3];
    float V = bv[0] + bv[1] + bv[2] + bv[3];
    atomicAdd(lossAcc, (double)L);
    atomicAdd(validAcc, (double)V);
  }
}

// K6: finalize loss = sum / max(valid, 1)
__global__ void k_final(const double* lossAcc, const double* validAcc, float* out) {
  double v = *validAcc;
  if (v < 1.0) v = 1.0;
  out[0] = (float)(*lossAcc / v);
}

extern "C" void kernel_launch(void* const* d_in, const int* in_sizes, int n_in,
                              void* d_out, int out_size, void* d_ws, size_t ws_size,
                              hipStream_t stream) {
  const float* emb = (const float*)d_in[0];
  const int* groups = (const int*)d_in[1];
  const void* mask = d_in[2];
  float* out = (float*)d_out;

  char* ws = (char*)d_ws;
  int* counts = (int*)(ws + OFF_COUNTS);
  int* starts = (int*)(ws + OFF_STARTS);
  int* vt = (int*)(ws + OFF_VT);
  double* lossAcc = (double*)(ws + OFF_LOSS);
  double* validAcc = (double*)(ws + OFF_VALID);
  int* order = (int*)(ws + OFF_ORDER);
  int* ghist = (int*)(ws + OFF_GHIST);

  // zero counts + accumulators (ws is poisoned 0xAA before each launch)
  hipMemsetAsync(ws, 0, 16408, stream);

  k_hist<<<NCHUNK, CHUNK, 0, stream>>>(groups, mask, counts, ghist);
  k_scan<<<1, 64, 0, stream>>>(counts, starts, vt);
  k_rebase<<<(NBINS + 3) / 4, 256, 0, stream>>>(starts, ghist);
  k_scatter<<<NCHUNK, CHUNK, 0, stream>>>(groups, mask, ghist, order);
  k_main<<<TOTAL / 128, 256, 0, stream>>>(emb, groups, mask, counts, starts,
                                          vt, order, lossAcc, validAcc);
  k_final<<<1, 1, 0, stream>>>(lossAcc, validAcc, out);
}

// Round 4
// 263.511 us; speedup vs baseline: 1.3758x; 1.2072x over previous
//
#include <hip/hip_runtime.h>
#include <stdint.h>

// Problem constants (match reference setup_inputs)
#define TOTAL  262144      // B*N = 16*16384
#define HALF   131072      // TOTAL/2 for threefry counter split
#define G      1024        // NUM_GROUPS
#define NBINS  1025        // groups 0..1023 + sentinel 1024 (masked)
#define NCHUNK 512         // chunks for counting sort
#define CHUNK  512         // elements per chunk

// workspace layout (bytes)
#define OFF_COUNTS 0               // int[1025]
#define OFF_STARTS 8192            // int[1025]
#define OFF_VT     16388           // int: valid_total
#define OFF_LOSS   16392           // double
#define OFF_VALID  16400           // double
#define OFF_SINK   16416           // float: prime-kernel DCE sink
#define OFF_ORDER  16448           // int[TOTAL]
#define OFF_GHIST  1065024         // int[NBINS*NCHUNK]  (~2.1 MB), g-major

// ---------------- threefry2x32 (JAX-compatible) ----------------
__device__ __forceinline__ void threefry2x32(uint32_t k0, uint32_t k1,
                                             uint32_t& x0, uint32_t& x1) {
  uint32_t ks0 = k0, ks1 = k1, ks2 = k0 ^ k1 ^ 0x1BD11BDAu;
#define TF_RND(R) { x0 += x1; x1 = (x1 << (R)) | (x1 >> (32 - (R))); x1 ^= x0; }
  x0 += ks0; x1 += ks1;
  TF_RND(13) TF_RND(15) TF_RND(26) TF_RND(6)
  x0 += ks1; x1 += ks2 + 1u;
  TF_RND(17) TF_RND(29) TF_RND(16) TF_RND(24)
  x0 += ks2; x1 += ks0 + 2u;
  TF_RND(13) TF_RND(15) TF_RND(26) TF_RND(6)
  x0 += ks0; x1 += ks1 + 3u;
  TF_RND(17) TF_RND(29) TF_RND(16) TF_RND(24)
  x0 += ks1; x1 += ks2 + 4u;
  TF_RND(13) TF_RND(15) TF_RND(26) TF_RND(6)
  x0 += ks2; x1 += ks0 + 5u;
#undef TF_RND
}

__device__ __forceinline__ int load_mask(const void* mask, int is8, int j) {
  return is8 ? (int)((const unsigned char*)mask)[j] : ((const int*)mask)[j];
}

// Per-wave self-detection of mask storage: int32 storage of 0/1 => all bytes
// at (addr%4)!=0 are zero. Probe bytes [0,256): 64 lanes x uchar4.
__device__ __forceinline__ int detect_is8(const void* mask) {
  int lane = threadIdx.x & 63;
  uchar4 p = ((const uchar4*)mask)[lane];
  unsigned long long bal = __ballot((p.y | p.z | p.w) != 0);
  return bal != 0ull;
}

// K1: per-chunk histogram -> ghist[g*NCHUNK + chunk]; also global counts.
__global__ __launch_bounds__(CHUNK) void k_hist(const int* __restrict__ groups,
                                                const void* __restrict__ mask,
                                                int* __restrict__ counts,
                                                int* __restrict__ ghist) {
  __shared__ int h[NBINS];
  int t = threadIdx.x;
  int is8 = detect_is8(mask);
  for (int b = t; b < NBINS; b += CHUNK) h[b] = 0;
  __syncthreads();
  int j = blockIdx.x * CHUNK + t;
  int m = load_mask(mask, is8, j);
  int g = m ? groups[j] : G;
  atomicAdd(&h[g], 1);
  __syncthreads();
  for (int b = t; b < NBINS; b += CHUNK) {
    int v = h[b];
    ghist[b * NCHUNK + blockIdx.x] = v;
    if (v) atomicAdd(&counts[b], v);
  }
}

// K2: exclusive scan of counts -> starts; valid_total. Single wave, no barriers.
__global__ __launch_bounds__(64) void k_scan(const int* __restrict__ counts,
                                             int* __restrict__ starts,
                                             int* __restrict__ vt) {
  int l = threadIdx.x;     // 64 lanes, 16 bins each (bins 0..1023)
  int c[16];
  int s = 0;
#pragma unroll
  for (int k = 0; k < 16; k++) { c[k] = counts[l * 16 + k]; s += c[k]; }
  int incl = s;
  for (int d = 1; d < 64; d <<= 1) {
    int tt = __shfl_up(incl, d);
    if (l >= d) incl += tt;
  }
  int run = incl - s;      // exclusive prefix
#pragma unroll
  for (int k = 0; k < 16; k++) { starts[l * 16 + k] = run; run += c[k]; }
  if (l == 63) starts[1024] = run;           // sum of bins 0..1023
  if (l == 0) *vt = TOTAL - counts[1024];
}

// K3: per-group exclusive scan over chunks (wave per group): ghist becomes chunk base.
__global__ __launch_bounds__(256) void k_rebase(const int* __restrict__ starts,
                                                int* __restrict__ ghist) {
  int wave = threadIdx.x >> 6, lane = threadIdx.x & 63;
  int g = blockIdx.x * 4 + wave;
  if (g >= NBINS) return;
  int* row = ghist + g * NCHUNK;
  int v[8];
  int s = 0;
  int bi = lane * 8;
#pragma unroll
  for (int k = 0; k < 8; k++) { v[k] = row[bi + k]; s += v[k]; }
  int incl = s;
  for (int d = 1; d < 64; d <<= 1) {
    int tt = __shfl_up(incl, d);
    if (lane >= d) incl += tt;
  }
  int run = starts[g] + (incl - s);
#pragma unroll
  for (int k = 0; k < 8; k++) { int tt = v[k]; row[bi + k] = run; run += tt; }
}

// K4: stable rank + scatter. Rank via 11-bit ballot match-any + per-wave
// leader counts in LDS.
__global__ __launch_bounds__(CHUNK) void k_scatter(const int* __restrict__ groups,
                                                   const void* __restrict__ mask,
                                                   const int* __restrict__ ghist,
                                                   int* __restrict__ order) {
  __shared__ int h[8][NBINS];          // 32.8 KB
  int t = threadIdx.x;
  int wave = t >> 6, lane = t & 63;
  int is8 = detect_is8(mask);
  int j = blockIdx.x * CHUNK + t;
  int m = load_mask(mask, is8, j);
  int g = m ? groups[j] : G;
  for (int idx = t; idx < 8 * NBINS; idx += CHUNK) ((int*)h)[idx] = 0;
  __syncthreads();
  unsigned long long mm = ~0ull;
#pragma unroll
  for (int b = 0; b < 11; b++) {
    unsigned long long bal = __ballot(((g >> b) & 1) != 0);
    mm &= ((g >> b) & 1) ? bal : ~bal;
  }
  unsigned long long lt = (1ull << lane) - 1ull;
  int lanerank = __popcll(mm & lt);
  if (lanerank == 0) h[wave][g] = __popcll(mm);   // unique (wave,g) writer
  __syncthreads();
  int rank = lanerank;
  for (int w = 0; w < wave; w++) rank += h[w][g];
  int pos = ghist[g * NCHUNK + blockIdx.x] + rank;
  order[pos] = j;
}

// K_prime: stream the whole embedding table coalesced to fill the memory-side
// Infinity Cache, converting k_main's compulsory fetch from random-row HBM
// (~0.9 TB/s) to streaming (~6 TB/s).
__global__ __launch_bounds__(256) void k_prime(const float4* __restrict__ e4,
                                               float* __restrict__ sink) {
  size_t n = (size_t)TOTAL * 32;           // 8M float4
  size_t stride = (size_t)gridDim.x * 256;
  float acc = 0.f;
  for (size_t idx = (size_t)blockIdx.x * 256 + threadIdx.x; idx < n; idx += stride) {
    float4 v = e4[idx];
    acc += v.x + v.y + v.z + v.w;
  }
  if (acc == 1.2345678e18f) sink[0] = acc;   // keeps loads live, never taken
}

// K5: main. Only sorted positions < valid_total do real work; blocks entirely
// in the masked tail return immediately (halves the gathered row set).
__global__ __launch_bounds__(256) void k_main(const float* __restrict__ emb,
                                              const int* __restrict__ groups,
                                              const void* __restrict__ mask,
                                              const int* __restrict__ counts,
                                              const int* __restrict__ starts,
                                              const int* __restrict__ vtp,
                                              const int* __restrict__ order,
                                              double* __restrict__ lossAcc,
                                              double* __restrict__ validAcc) {
  __shared__ int mA[128], mP[128], mN[128], mF[128];
  __shared__ float bl[4], bv[4];
  int t = threadIdx.x;
  int wave = t >> 6, lane = t & 63;
  int vt = *vtp;
  int P0 = blockIdx.x * 128;
  if (P0 >= vt) return;                    // fully-masked tail block
  int is8 = detect_is8(mask);

  // ---- Phase A: lanes 0..31 compute metadata for position P0 + wave*32 + lane
  if (lane < 32) {
    int i = P0 + wave * 32 + lane;
    int slot = wave * 32 + lane;
    if (i < vt) {
      int j = order[i];
      int mm2 = load_mask(mask, is8, j);
      int g = mm2 ? groups[j] : G;
      int cnt = counts[g], st = starts[g];
      int local = i - st;
      int partner_pos = (local == 0) ? (st + cnt - 1) : (i - 1);
      int pos_idx = order[partner_pos];

      uint32_t x0, x1;
      if (i < HALF) { x0 = (uint32_t)i; x1 = (uint32_t)(i + HALF); }
      else          { x0 = (uint32_t)(i - HALF); x1 = (uint32_t)i; }
      threefry2x32(0u, 42u, x0, x1);
      uint32_t bits = (i < HALF) ? x0 : x1;
      float u = __uint_as_float((bits >> 9) | 0x3F800000u) - 1.0f;

      int compi = vt - cnt;
      int comp = compi > 1 ? compi : 1;
      int r = (int)(u * (float)comp);
      int cm1 = comp - 1;
      if (r > cm1) r = cm1;
      int neg_pos = (r < st) ? r : (r + cnt);
      if (neg_pos < 0) neg_pos = 0;
      if (neg_pos > TOTAL - 1) neg_pos = TOTAL - 1;
      int neg_idx = order[neg_pos];
      int valid = (g < G) && (cnt >= 2) && (compi > 0);
      int shufok = (partner_pos == i - 1);

      mA[slot] = j; mP[slot] = pos_idx; mN[slot] = neg_idx;
      mF[slot] = valid | (shufok << 1);
    } else {
      // masked-tail straddle: dummy row 0 (uniform cached load), contributes 0
      mA[slot] = 0; mP[slot] = 0; mN[slot] = 0; mF[slot] = 0;
    }
  }
  __syncthreads();

  // ---- Phase B
  int sg = lane >> 3, sl = lane & 7;
  const float4* e4 = (const float4*)emb;   // row stride = 32 float4
  float lsum = 0.f, vsum = 0.f;
#pragma unroll 1
  for (int it = 0; it < 4; it++) {
    int slot = wave * 32 + it * 8 + sg;
    int ai = mA[slot], pi = mP[slot], ni = mN[slot], fl = mF[slot];
    const float4* ar = e4 + (size_t)ai * 32 + sl * 4;
    const float4* nr = e4 + (size_t)ni * 32 + sl * 4;
    float4 a0 = ar[0], a1 = ar[1], a2 = ar[2], a3 = ar[3];
    float4 n0 = nr[0], n1 = nr[1], n2 = nr[2], n3 = nr[3];
    // positive fragment = neighbor group's anchor fragment
    float4 p0, p1, p2, p3;
    p0.x = __shfl_up(a0.x, 8); p0.y = __shfl_up(a0.y, 8);
    p0.z = __shfl_up(a0.z, 8); p0.w = __shfl_up(a0.w, 8);
    p1.x = __shfl_up(a1.x, 8); p1.y = __shfl_up(a1.y, 8);
    p1.z = __shfl_up(a1.z, 8); p1.w = __shfl_up(a1.w, 8);
    p2.x = __shfl_up(a2.x, 8); p2.y = __shfl_up(a2.y, 8);
    p2.z = __shfl_up(a2.z, 8); p2.w = __shfl_up(a2.w, 8);
    p3.x = __shfl_up(a3.x, 8); p3.y = __shfl_up(a3.y, 8);
    p3.z = __shfl_up(a3.z, 8); p3.w = __shfl_up(a3.w, 8);
    int useshuf = (sg > 0) && (fl & 2);
    if (!useshuf) {
      const float4* pr = e4 + (size_t)pi * 32 + sl * 4;
      p0 = pr[0]; p1 = pr[1]; p2 = pr[2]; p3 = pr[3];
    }
    float ap0 = a0.x*p0.x + a0.y*p0.y + a0.z*p0.z + a0.w*p0.w
              + a1.x*p1.x + a1.y*p1.y + a1.z*p1.z + a1.w*p1.w;
    float ap1 = a2.x*p2.x + a2.y*p2.y + a2.z*p2.z + a2.w*p2.w
              + a3.x*p3.x + a3.y*p3.y + a3.z*p3.z + a3.w*p3.w;
    float an0 = a0.x*n0.x + a0.y*n0.y + a0.z*n0.z + a0.w*n0.w
              + a1.x*n1.x + a1.y*n1.y + a1.z*n1.z + a1.w*n1.w;
    float an1 = a2.x*n2.x + a2.y*n2.y + a2.z*n2.z + a2.w*n2.w
              + a3.x*n3.x + a3.y*n3.y + a3.z*n3.z + a3.w*n3.w;
    float ap = ap0 + ap1, an = an0 + an1;
    ap += __shfl_xor(ap, 4); an += __shfl_xor(an, 4);
    ap += __shfl_xor(ap, 2); an += __shfl_xor(an, 2);
    ap += __shfl_xor(ap, 1); an += __shfl_xor(an, 1);
    if ((fl & 1) && sl == 0) {
      float ps = ap * 10.0f, ns = an * 10.0f;   // 1/TEMPERATURE
      float dd = ns - ps;
      float li = fmaxf(dd, 0.0f) + log1pf(expf(-fabsf(dd)));
      lsum += li; vsum += 1.0f;
    }
  }
  // wave reduce, then one atomic pair per block
  for (int d = 32; d >= 1; d >>= 1) {
    lsum += __shfl_xor(lsum, d);
    vsum += __shfl_xor(vsum, d);
  }
  if (lane == 0) { bl[wave] = lsum; bv[wave] = vsum; }
  __syncthreads();
  if (t == 0) {
    float L = bl[0] + bl[1] + bl[2] + bl[3];
    float V = bv[0] + bv[1] + bv[2] + bv[3];
    atomicAdd(lossAcc, (double)L);
    atomicAdd(validAcc, (double)V);
  }
}

// K6: finalize loss = sum / max(valid, 1)
__global__ void k_final(const double* lossAcc, const double* validAcc, float* out) {
  double v = *validAcc;
  if (v < 1.0) v = 1.0;
  out[0] = (float)(*lossAcc / v);
}

extern "C" void kernel_launch(void* const* d_in, const int* in_sizes, int n_in,
                              void* d_out, int out_size, void* d_ws, size_t ws_size,
                              hipStream_t stream) {
  const float* emb = (const float*)d_in[0];
  const int* groups = (const int*)d_in[1];
  const void* mask = d_in[2];
  float* out = (float*)d_out;

  char* ws = (char*)d_ws;
  int* counts = (int*)(ws + OFF_COUNTS);
  int* starts = (int*)(ws + OFF_STARTS);
  int* vt = (int*)(ws + OFF_VT);
  double* lossAcc = (double*)(ws + OFF_LOSS);
  double* validAcc = (double*)(ws + OFF_VALID);
  float* sink = (float*)(ws + OFF_SINK);
  int* order = (int*)(ws + OFF_ORDER);
  int* ghist = (int*)(ws + OFF_GHIST);

  // zero counts + accumulators (ws is poisoned 0xAA before each launch)
  hipMemsetAsync(ws, 0, 16408, stream);

  k_hist<<<NCHUNK, CHUNK, 0, stream>>>(groups, mask, counts, ghist);
  k_scan<<<1, 64, 0, stream>>>(counts, starts, vt);
  k_rebase<<<(NBINS + 3) / 4, 256, 0, stream>>>(starts, ghist);
  k_scatter<<<NCHUNK, CHUNK, 0, stream>>>(groups, mask, ghist, order);
  k_prime<<<2048, 256, 0, stream>>>((const float4*)emb, sink);
  k_main<<<TOTAL / 128, 256, 0, stream>>>(emb, groups, mask, counts, starts,
                                          vt, order, lossAcc, validAcc);
  k_final<<<1, 1, 0, stream>>>(lossAcc, validAcc, out);
}